// Round 4
// baseline (172.906 us; speedup 1.0000x reference)
//
#include <hip/hip_runtime.h>

// B=8, N=256, M=16, D=256
// loss = sum_rows logsumexp_k(S) - sum S_self, S = w*<e,c_k>+b, LOO diagonal
constexpr int B = 8, N = 256, M = 16, D = 256;

typedef short bf16x8 __attribute__((ext_vector_type(8)));
typedef float f32x4 __attribute__((ext_vector_type(4)));

__device__ __forceinline__ unsigned short f2bf(float x) {
  unsigned u = __float_as_uint(x);
  u = (u + 0x7FFFu + ((u >> 16) & 1u)) >> 16;  // RNE
  return (unsigned short)u;
}
__device__ __forceinline__ uint4 packbf8(const float* f) {
  uint4 u;
  u.x = (unsigned)f2bf(f[0]) | ((unsigned)f2bf(f[1]) << 16);
  u.y = (unsigned)f2bf(f[2]) | ((unsigned)f2bf(f[3]) << 16);
  u.z = (unsigned)f2bf(f[4]) | ((unsigned)f2bf(f[5]) << 16);
  u.w = (unsigned)f2bf(f[6]) | ((unsigned)f2bf(f[7]) << 16);
  return u;
}

// ws layout: Cbf [0,1MB) B-frags uint4[(b*8+kc)*16+nt][lane], lane l = col
//   n=nt*16+(l&15), dims kc*32+(l>>4)*8..+7.  flags [1MB,+2KB) one u32 per block
//   (memset to 0 each launch).  Fallback-only: EbfA [2MB,18MB), SQ [18MB,+128KB).

// ============================================================================
// Fused single-dispatch kernel, custom grid barrier (replaces cg::sync, which
// measured ~73 us in round 2; numeric phases byte-identical to the verified
// round-2 k_fused, absmax 0.0).
// Barrier: writer side = per-block release flag (threadfence -> wbl2, then
// relaxed agent store; no same-address RMW chain). Reader side = wave 0 spins
// on ONE coalesced 64-lane agent load of its batch's 64 flags, then a single
// threadfence (buffer_inv) before touching remote-written Cbf.
// Cooperative launch is used only for the co-residency guarantee.
// ============================================================================
__global__ __launch_bounds__(256, 2) void k_fused2(const float* __restrict__ e,
                                                   uint4* __restrict__ Cbf,
                                                   unsigned* __restrict__ flags,
                                                   const float* __restrict__ wp,
                                                   const float* __restrict__ bp,
                                                   float* __restrict__ out) {
  const int blk = blockIdx.x;  // b*64 + strip
  const int b = blk >> 6, strip = blk & 63;
  const int tid = threadIdx.x;
  const int wid = tid >> 6, lane = tid & 63;

  __shared__ uint4 A_lds[4 * 8 * 64];  // 32 KB: [jt][kc][lane]
  __shared__ float cbuf[4][D];         // 4 KB: per-wave centroid (already /16)
  __shared__ float sql[64];            // row sqnorms for this block's 64 rows
  __shared__ float lmx[2][64];
  __shared__ float lsm[2][64];
  __shared__ float bred[4];

  // ---- Phase 1 (verified round-2 code) ----
  {
    const int j = strip * 4 + wid;
    const float* base = e + (size_t)(b * 256 + j) * (M * D);

    // centroid: lane owns dims 4*lane..+3; 16 coalesced 1KB wave-loads.
    float4 cv = {0.f, 0.f, 0.f, 0.f};
#pragma unroll
    for (int i = 0; i < M; ++i) {
      float4 v = *(const float4*)(base + i * D + lane * 4);
      cv.x += v.x; cv.y += v.y; cv.z += v.z; cv.w += v.w;
    }
    cv.x *= (1.f / 16.f); cv.y *= (1.f / 16.f);
    cv.z *= (1.f / 16.f); cv.w *= (1.f / 16.f);
    *(float4*)&cbuf[wid][lane * 4] = cv;

    // A-frags + sqnorm: lane -> row m=lane&15, octet q=lane>>4; L1-hot re-read.
    const int m = lane & 15, q = lane >> 4;
    const float* rp = base + m * D + q * 8;
    float sqp = 0.f;
#pragma unroll
    for (int kc = 0; kc < 8; ++kc) {
      float f[8];
      *(float4*)(f) = *(const float4*)(rp + kc * 32);
      *(float4*)(f + 4) = *(const float4*)(rp + kc * 32 + 4);
      A_lds[(wid * 8 + kc) * 64 + lane] = packbf8(f);
#pragma unroll
      for (int x = 0; x < 8; ++x) sqp = fmaf(f[x], f[x], sqp);
    }
    sqp += __shfl_xor(sqp, 16, 64);
    sqp += __shfl_xor(sqp, 32, 64);
    if (q == 0) sql[wid * 16 + m] = sqp;
  }
  __syncthreads();  // cbuf/A_lds/sql visible block-wide

  // B-frag write: lanes 0..31 of wave wid pack its centroid j into Cbf.
  if (lane < 32) {
    const int j = strip * 4 + wid;
    float cf[8];
#pragma unroll
    for (int x = 0; x < 8; ++x) cf[x] = cbuf[wid][lane * 8 + x];
    Cbf[((size_t)(b * 8 + (lane >> 2)) * 16 + (j >> 4)) * 64 + (lane & 3) * 16 +
        (j & 15)] = packbf8(cf);
  }
  if (blk == 0 && tid == 0) out[0] = 0.f;  // d_out re-poisoned each launch

  // ---- custom grid barrier ----
  __syncthreads();  // all waves' Cbf stores drained (vmcnt(0) before s_barrier)
  if (tid == 0) {
    __threadfence();  // wbl2: this block's Cbf writes reach agent scope
    __hip_atomic_store(&flags[blk], 1u, __ATOMIC_RELAXED, __HIP_MEMORY_SCOPE_AGENT);
  }
  if (wid == 0) {
    const unsigned* fb = flags + b * 64;  // this batch's 64 writer blocks
    int spins = 0;
    for (;;) {
      unsigned v = __hip_atomic_load(&fb[lane], __ATOMIC_RELAXED,
                                     __HIP_MEMORY_SCOPE_AGENT);
      if (__all(v != 0)) break;
      __builtin_amdgcn_s_sleep(2);
      if (++spins > (1 << 22)) break;  // safety valve; unreachable (co-resident)
    }
  }
  __syncthreads();
  __threadfence();  // invalidate stale L1/L2 before reading remote Cbf

  // ---- Phase 2: GEMM + epilogue (verified round-2 code) ----
  const int h = wid >> 1, c = wid & 1;
  const int q = lane >> 4, cl_ = lane & 15;
  const uint4* Bb = Cbf + (size_t)(b * 128 + c * 8) * 64 + lane;

  f32x4 acc[2][8];
#pragma unroll
  for (int rt = 0; rt < 2; ++rt)
#pragma unroll
    for (int nt = 0; nt < 8; ++nt) acc[rt][nt] = (f32x4)0.f;

#pragma unroll 1
  for (int kc = 0; kc < 8; ++kc) {
    uint4 af0 = A_lds[((h * 2) * 8 + kc) * 64 + lane];
    uint4 af1 = A_lds[((h * 2 + 1) * 8 + kc) * 64 + lane];
    uint4 bfr[8];
#pragma unroll
    for (int nt = 0; nt < 8; ++nt) bfr[nt] = Bb[(kc * 16 + nt) * 64];
    bf16x8 a0 = __builtin_bit_cast(bf16x8, af0);
    bf16x8 a1 = __builtin_bit_cast(bf16x8, af1);
#pragma unroll
    for (int nt = 0; nt < 8; ++nt) {
      bf16x8 bv = __builtin_bit_cast(bf16x8, bfr[nt]);
      acc[0][nt] = __builtin_amdgcn_mfma_f32_16x16x32_bf16(a0, bv, acc[0][nt], 0, 0, 0);
      acc[1][nt] = __builtin_amdgcn_mfma_f32_16x16x32_bf16(a1, bv, acc[1][nt], 0, 0, 0);
    }
  }

  const float w = *wp, bias = *bp;
  float ssum = 0.f;

#pragma unroll
  for (int rt = 0; rt < 2; ++rt) {
    const int jr = strip * 4 + h * 2 + rt;  // global row-tile == diag col
    const bool own = (c == (jr >> 7)) && (cl_ == (jr & 15));
    const int ntd = (jr >> 4) & 7;
    float sq[4];
    if (own) {
#pragma unroll
      for (int reg = 0; reg < 4; ++reg)
        sq[reg] = sql[(h * 2 + rt) * 16 + q * 4 + reg];
    }
#pragma unroll
    for (int nt = 0; nt < 8; ++nt)
#pragma unroll
      for (int reg = 0; reg < 4; ++reg) {
        const float raw = acc[rt][nt][reg];
        float sv = fmaf(w, raw, bias);
        if (own && nt == ntd) {  // predicated select, no indexing
          sv = fmaf(w * (1.f / 15.f), 16.f * raw - sq[reg], bias);
          ssum += sv;
        }
        acc[rt][nt][reg] = sv;
      }
#pragma unroll
    for (int reg = 0; reg < 4; ++reg) {
      float mx = acc[rt][0][reg];
#pragma unroll
      for (int nt = 1; nt < 8; ++nt) mx = fmaxf(mx, acc[rt][nt][reg]);
#pragma unroll
      for (int mk = 1; mk < 16; mk <<= 1) mx = fmaxf(mx, __shfl_xor(mx, mk, 64));
      if (cl_ == 0) lmx[c][(h * 2 + rt) * 16 + q * 4 + reg] = mx;
    }
  }
  __syncthreads();

#pragma unroll
  for (int rt = 0; rt < 2; ++rt)
#pragma unroll
    for (int reg = 0; reg < 4; ++reg) {
      const int Rl = (h * 2 + rt) * 16 + q * 4 + reg;
      const float mx = fmaxf(lmx[0][Rl], lmx[1][Rl]);
      float se = 0.f;
#pragma unroll
      for (int nt = 0; nt < 8; ++nt) se += __expf(acc[rt][nt][reg] - mx);
#pragma unroll
      for (int mk = 1; mk < 16; mk <<= 1) se += __shfl_xor(se, mk, 64);
      if (cl_ == 0) lsm[c][Rl] = se;
    }
  __syncthreads();

  float part = -ssum;
  if (c == 0 && cl_ == 0) {
#pragma unroll
    for (int rt = 0; rt < 2; ++rt)
#pragma unroll
      for (int reg = 0; reg < 4; ++reg) {
        const int Rl = (h * 2 + rt) * 16 + q * 4 + reg;
        const float mx = fmaxf(lmx[0][Rl], lmx[1][Rl]);
        part += mx + __logf(lsm[0][Rl] + lsm[1][Rl]);
      }
  }
#pragma unroll
  for (int mk = 1; mk < 64; mk <<= 1) part += __shfl_xor(part, mk, 64);
  if (lane == 0) bred[wid] = part;
  __syncthreads();
  if (tid == 0) atomicAdd(out, bred[0] + bred[1] + bred[2] + bred[3]);
}

// ============================================================================
// FALLBACK path (bit-identical to the round-1 verified two-kernel version,
// 96.3 us). Used only if the cooperative launch is rejected.
// ============================================================================
__global__ __launch_bounds__(256) void k_prep(const float* __restrict__ e,
                                              uint4* __restrict__ EbfA,
                                              uint4* __restrict__ Cbf,
                                              float* __restrict__ SQ,
                                              float* __restrict__ out) {
  const int blk = blockIdx.x;  // b*256 + j
  const int b = blk >> 8, j = blk & 255;
  const int t = threadIdx.x;
  const float* base = e + (size_t)blk * (M * D);

  __shared__ float cbuf[D];
  __shared__ float sqred[4][16];

  float cs = 0.f;
#pragma unroll
  for (int i = 0; i < M; ++i) cs += base[i * D + t];
  cbuf[t] = cs * (1.f / 16.f);

  const int m = t & 15, o2 = t >> 4;
  const float* p0 = base + m * D + o2 * 8;
  float f0[8], f1[8];
  *(float4*)(f0) = *(const float4*)(p0);
  *(float4*)(f0 + 4) = *(const float4*)(p0 + 4);
  *(float4*)(f1) = *(const float4*)(p0 + 128);
  *(float4*)(f1 + 4) = *(const float4*)(p0 + 132);

  EbfA[(size_t)(blk * 8 + (o2 >> 2)) * 64 + (o2 & 3) * 16 + m] = packbf8(f0);
  EbfA[(size_t)(blk * 8 + 4 + (o2 >> 2)) * 64 + (o2 & 3) * 16 + m] = packbf8(f1);

  float sqp = 0.f;
#pragma unroll
  for (int x = 0; x < 8; ++x) sqp = fmaf(f0[x], f0[x], fmaf(f1[x], f1[x], sqp));
  sqp += __shfl_xor(sqp, 16, 64);
  sqp += __shfl_xor(sqp, 32, 64);
  const int w = t >> 6;
  if ((t & 63) < 16) sqred[w][m] = sqp;
  __syncthreads();

  if (t < 32) {
    float cf[8];
#pragma unroll
    for (int x = 0; x < 8; ++x) cf[x] = cbuf[t * 8 + x];
    Cbf[((size_t)(b * 8 + (t >> 2)) * 16 + (j >> 4)) * 64 + (t & 3) * 16 + (j & 15)] =
        packbf8(cf);
  }
  if (t < 16) SQ[blk * 16 + t] = sqred[0][t] + sqred[1][t] + sqred[2][t] + sqred[3][t];
  if (blk == 0 && t == 0) out[0] = 0.f;
}

__global__ __launch_bounds__(256) void k_gemm(const uint4* __restrict__ EbfA,
                                              const uint4* __restrict__ Cbf,
                                              const float* __restrict__ SQ,
                                              const float* __restrict__ wp,
                                              const float* __restrict__ bp,
                                              float* __restrict__ out) {
  const int blk = blockIdx.x;  // b*64 + strip
  const int b = blk >> 6, strip = blk & 63;
  const int tid = threadIdx.x;
  const int wid = tid >> 6, lane = tid & 63;
  const int h = wid >> 1, c = wid & 1;
  const int q = lane >> 4, cl_ = lane & 15;

  const uint4* Ab = EbfA + (size_t)((b * 256 + strip * 4 + h * 2) * 8) * 64 + lane;
  const uint4* Bb = Cbf + (size_t)(b * 128 + c * 8) * 64 + lane;

  f32x4 acc[2][8];
#pragma unroll
  for (int rt = 0; rt < 2; ++rt)
#pragma unroll
    for (int nt = 0; nt < 8; ++nt) acc[rt][nt] = (f32x4)0.f;

#pragma unroll 1
  for (int kc = 0; kc < 8; ++kc) {
    uint4 af0 = Ab[kc * 64];
    uint4 af1 = Ab[(8 + kc) * 64];
    uint4 bfr[8];
#pragma unroll
    for (int nt = 0; nt < 8; ++nt) bfr[nt] = Bb[(kc * 16 + nt) * 64];
    bf16x8 a0 = __builtin_bit_cast(bf16x8, af0);
    bf16x8 a1 = __builtin_bit_cast(bf16x8, af1);
#pragma unroll
    for (int nt = 0; nt < 8; ++nt) {
      bf16x8 bv = __builtin_bit_cast(bf16x8, bfr[nt]);
      acc[0][nt] = __builtin_amdgcn_mfma_f32_16x16x32_bf16(a0, bv, acc[0][nt], 0, 0, 0);
      acc[1][nt] = __builtin_amdgcn_mfma_f32_16x16x32_bf16(a1, bv, acc[1][nt], 0, 0, 0);
    }
  }

  const float w = *wp, bias = *bp;
  __shared__ float lmx[2][64];
  __shared__ float lsm[2][64];
  __shared__ float bred[4];
  float ssum = 0.f;

#pragma unroll
  for (int rt = 0; rt < 2; ++rt) {
    const int jr = strip * 4 + h * 2 + rt;
    const bool own = (c == (jr >> 7)) && (cl_ == (jr & 15));
    const int ntd = (jr >> 4) & 7;
    float sq[4];
    if (own) {
#pragma unroll
      for (int reg = 0; reg < 4; ++reg)
        sq[reg] = SQ[b * 4096 + strip * 64 + (h * 2 + rt) * 16 + q * 4 + reg];
    }
#pragma unroll
    for (int nt = 0; nt < 8; ++nt)
#pragma unroll
      for (int reg = 0; reg < 4; ++reg) {
        const float raw = acc[rt][nt][reg];
        float sv = fmaf(w, raw, bias);
        if (own && nt == ntd) {
          sv = fmaf(w * (1.f / 15.f), 16.f * raw - sq[reg], bias);
          ssum += sv;
        }
        acc[rt][nt][reg] = sv;
      }
#pragma unroll
    for (int reg = 0; reg < 4; ++reg) {
      float mx = acc[rt][0][reg];
#pragma unroll
      for (int nt = 1; nt < 8; ++nt) mx = fmaxf(mx, acc[rt][nt][reg]);
#pragma unroll
      for (int mk = 1; mk < 16; mk <<= 1) mx = fmaxf(mx, __shfl_xor(mx, mk, 64));
      if (cl_ == 0) lmx[c][(h * 2 + rt) * 16 + q * 4 + reg] = mx;
    }
  }
  __syncthreads();

#pragma unroll
  for (int rt = 0; rt < 2; ++rt)
#pragma unroll
    for (int reg = 0; reg < 4; ++reg) {
      const int Rl = (h * 2 + rt) * 16 + q * 4 + reg;
      const float mx = fmaxf(lmx[0][Rl], lmx[1][Rl]);
      float se = 0.f;
#pragma unroll
      for (int nt = 0; nt < 8; ++nt) se += __expf(acc[rt][nt][reg] - mx);
#pragma unroll
      for (int mk = 1; mk < 16; mk <<= 1) se += __shfl_xor(se, mk, 64);
      if (cl_ == 0) lsm[c][Rl] = se;
    }
  __syncthreads();

  float part = -ssum;
  if (c == 0 && cl_ == 0) {
#pragma unroll
    for (int rt = 0; rt < 2; ++rt)
#pragma unroll
      for (int reg = 0; reg < 4; ++reg) {
        const int Rl = (h * 2 + rt) * 16 + q * 4 + reg;
        const float mx = fmaxf(lmx[0][Rl], lmx[1][Rl]);
        part += mx + __logf(lsm[0][Rl] + lsm[1][Rl]);
      }
  }
#pragma unroll
  for (int mk = 1; mk < 64; mk <<= 1) part += __shfl_xor(part, mk, 64);
  if (lane == 0) bred[wid] = part;
  __syncthreads();
  if (tid == 0) atomicAdd(out, bred[0] + bred[1] + bred[2] + bred[3]);
}

extern "C" void kernel_launch(void* const* d_in, const int* in_sizes, int n_in,
                              void* d_out, int out_size, void* d_ws, size_t ws_size,
                              hipStream_t stream) {
  const float* e = (const float*)d_in[0];
  const float* wp = (const float*)d_in[1];
  const float* bp = (const float*)d_in[2];
  float* out = (float*)d_out;
  char* ws = (char*)d_ws;
  uint4* Cbf = (uint4*)ws;                                    // 1 MB
  unsigned* flags = (unsigned*)(ws + (size_t)1024 * 1024);    // 2 KB
  uint4* EbfA = (uint4*)(ws + (size_t)2 * 1024 * 1024);       // 16 MB (fallback)
  float* SQ = (float*)(ws + (size_t)18 * 1024 * 1024);        // 128 KB (fallback)

  hipMemsetAsync(flags, 0, B * 64 * sizeof(unsigned), stream);

  void* args[] = {(void*)&e, (void*)&Cbf, (void*)&flags,
                  (void*)&wp, (void*)&bp, (void*)&out};
  hipError_t err = hipLaunchCooperativeKernel((const void*)k_fused2, dim3(B * 64),
                                              dim3(256), args, 0, stream);
  if (err != hipSuccess) {
    // cooperative launch unavailable -> verified 2-kernel path
    k_prep<<<B * N, 256, 0, stream>>>(e, EbfA, Cbf, SQ, out);
    k_gemm<<<B * 64, 256, 0, stream>>>(EbfA, Cbf, SQ, wp, bp, out);
  }
}

// Round 5
// 102.650 us; speedup vs baseline: 1.6844x; 1.6844x over previous
//
#include <hip/hip_runtime.h>

// B=8, N=256, M=16, D=256
// loss = sum_rows logsumexp_k(S) - sum S_self, S = w*<e,c_k>+b, LOO diagonal
constexpr int B = 8, N = 256, M = 16, D = 256;

typedef short bf16x8 __attribute__((ext_vector_type(8)));
typedef float f32x4 __attribute__((ext_vector_type(4)));

__device__ __forceinline__ unsigned short f2bf(float x) {
  unsigned u = __float_as_uint(x);
  u = (u + 0x7FFFu + ((u >> 16) & 1u)) >> 16;  // RNE
  return (unsigned short)u;
}
__device__ __forceinline__ uint4 packbf8(const float* f) {
  uint4 u;
  u.x = (unsigned)f2bf(f[0]) | ((unsigned)f2bf(f[1]) << 16);
  u.y = (unsigned)f2bf(f[2]) | ((unsigned)f2bf(f[3]) << 16);
  u.z = (unsigned)f2bf(f[4]) | ((unsigned)f2bf(f[5]) << 16);
  u.w = (unsigned)f2bf(f[6]) | ((unsigned)f2bf(f[7]) << 16);
  return u;
}

// ws: Cbf [0,1MB) B-frags: uint4[(b*8+kc)*16+nt][lane], lane l = col n=nt*16+(l&15),
//     dims kc*32+(l>>4)*8..+7.  (No other workspace: A-frags live in LDS only.)

// k_cent: one block per (b,j) [2048 blocks, high occupancy]. Centroid only —
// thread t owns dim d=t, serial sum over M=16 rows (16 coalesced 1KB wave-loads),
// then threads 0..31 pack the bf16 B-fragment. Verbatim round-3 verified code.
__global__ __launch_bounds__(256) void k_cent(const float* __restrict__ e,
                                              uint4* __restrict__ Cbf,
                                              float* __restrict__ out) {
  const int blk = blockIdx.x;  // b*256 + j
  const int b = blk >> 8, j = blk & 255;
  const int t = threadIdx.x;
  const float* base = e + (size_t)blk * (M * D);

  __shared__ float cbuf[D];
  float cs = 0.f;
#pragma unroll
  for (int i = 0; i < M; ++i) cs += base[i * D + t];
  cbuf[t] = cs * (1.f / 16.f);
  __syncthreads();

  if (t < 32) {
    float cf[8];
#pragma unroll
    for (int x = 0; x < 8; ++x) cf[x] = cbuf[t * 8 + x];
    Cbf[((size_t)(b * 8 + (t >> 2)) * 16 + (j >> 4)) * 64 + (t & 3) * 16 + (j & 15)] =
        packbf8(cf);
  }
  if (blk == 0 && t == 0) out[0] = 0.f;  // d_out re-poisoned each launch
}

// k_gemm3: 1024 blocks = (b, pair p of 2 j's), 256 threads, 4 waves.
// Wave (jt=wid>>1, half=wid&1).
// Phase 1: wave packs A-frags of j=p*2+jt for kc in [half*4, half*4+4) from e
//   (L3-hot after k_cent) into LDS; per-half row sqnorms into sqh.
// Phase 2: wave (jt, c=half) computes rows of j=p*2+jt vs col-half c (8 nt) —
//   verified GEMM + LOO/logsumexp epilogue, re-indexed for 1 row-tile per wave.
// Occupancy: grid 1024 -> 4 blocks/CU = 16 waves/CU (fixes r3/r4's 260 GB/s
// latency-bound phase 1: 8 independent loads in flight per wave, no VGPR cap).
__global__ __launch_bounds__(256) void k_gemm3(const float* __restrict__ e,
                                               const uint4* __restrict__ Cbf,
                                               const float* __restrict__ wp,
                                               const float* __restrict__ bp,
                                               float* __restrict__ out) {
  const int blk = blockIdx.x;  // b*128 + p
  const int b = blk >> 7, p = blk & 127;
  const int tid = threadIdx.x;
  const int wid = tid >> 6, lane = tid & 63;
  const int jt = wid >> 1, half = wid & 1;

  __shared__ uint4 A_lds[2 * 8 * 64];  // 16 KB: [jt][kc][lane]
  __shared__ float sqh[2][2][16];      // [jt][half][m] partial row sqnorms
  __shared__ float lmx[2][32];
  __shared__ float lsm[2][32];
  __shared__ float bred[4];

  // ---- Phase 1: A-frag pack + sqnorm (2 waves per j, disjoint kc halves) ----
  {
    const int j = p * 2 + jt;
    const float* base = e + (size_t)(b * 256 + j) * (M * D);
    const int m = lane & 15, q = lane >> 4;
    const float* rp = base + m * D + q * 8;
    float sqp = 0.f;
#pragma unroll
    for (int kk = 0; kk < 4; ++kk) {
      const int kc = half * 4 + kk;
      float f[8];
      *(float4*)(f) = *(const float4*)(rp + kc * 32);
      *(float4*)(f + 4) = *(const float4*)(rp + kc * 32 + 4);
      A_lds[(jt * 8 + kc) * 64 + lane] = packbf8(f);
#pragma unroll
      for (int x = 0; x < 8; ++x) sqp = fmaf(f[x], f[x], sqp);
    }
    // reduce over q (lane bits 4,5): same-m lanes hold disjoint octets.
    sqp += __shfl_xor(sqp, 16, 64);
    sqp += __shfl_xor(sqp, 32, 64);
    if (q == 0) sqh[jt][half][m] = sqp;
  }
  __syncthreads();  // A_lds/sqh visible block-wide

  // ---- Phase 2: GEMM + epilogue ----
  const int c = half;  // wave's column-half role
  const int q = lane >> 4, cl_ = lane & 15;
  const uint4* Bb = Cbf + (size_t)(b * 128 + c * 8) * 64 + lane;

  f32x4 acc[8];
#pragma unroll
  for (int nt = 0; nt < 8; ++nt) acc[nt] = (f32x4)0.f;

#pragma unroll 1
  for (int kc = 0; kc < 8; ++kc) {
    uint4 af = A_lds[(jt * 8 + kc) * 64 + lane];
    uint4 bfr[8];
#pragma unroll
    for (int nt = 0; nt < 8; ++nt) bfr[nt] = Bb[(kc * 16 + nt) * 64];
    bf16x8 a = __builtin_bit_cast(bf16x8, af);
#pragma unroll
    for (int nt = 0; nt < 8; ++nt) {
      bf16x8 bv = __builtin_bit_cast(bf16x8, bfr[nt]);
      acc[nt] = __builtin_amdgcn_mfma_f32_16x16x32_bf16(a, bv, acc[nt], 0, 0, 0);
    }
  }

  const float w = *wp, bias = *bp;
  float ssum = 0.f;
  const int jr = p * 2 + jt;  // this wave's row-group j == diag col
  const bool own = (c == (jr >> 7)) && (cl_ == (jr & 15));
  const int ntd = (jr >> 4) & 7;
  float sq[4];
  if (own) {
#pragma unroll
    for (int reg = 0; reg < 4; ++reg)
      sq[reg] = sqh[jt][0][q * 4 + reg] + sqh[jt][1][q * 4 + reg];
  }
#pragma unroll
  for (int nt = 0; nt < 8; ++nt)
#pragma unroll
    for (int reg = 0; reg < 4; ++reg) {
      const float raw = acc[nt][reg];
      float sv = fmaf(w, raw, bias);
      if (own && nt == ntd) {  // predicated select, no indexing
        sv = fmaf(w * (1.f / 15.f), 16.f * raw - sq[reg], bias);
        ssum += sv;
      }
      acc[nt][reg] = sv;
    }
#pragma unroll
  for (int reg = 0; reg < 4; ++reg) {
    float mx = acc[0][reg];
#pragma unroll
    for (int nt = 1; nt < 8; ++nt) mx = fmaxf(mx, acc[nt][reg]);
#pragma unroll
    for (int mk = 1; mk < 16; mk <<= 1) mx = fmaxf(mx, __shfl_xor(mx, mk, 64));
    if (cl_ == 0) lmx[c][jt * 16 + q * 4 + reg] = mx;
  }
  __syncthreads();

#pragma unroll
  for (int reg = 0; reg < 4; ++reg) {
    const int Rl = jt * 16 + q * 4 + reg;
    const float mx = fmaxf(lmx[0][Rl], lmx[1][Rl]);
    float se = 0.f;
#pragma unroll
    for (int nt = 0; nt < 8; ++nt) se += __expf(acc[nt][reg] - mx);
#pragma unroll
    for (int mk = 1; mk < 16; mk <<= 1) se += __shfl_xor(se, mk, 64);
    if (cl_ == 0) lsm[c][Rl] = se;
  }
  __syncthreads();

  float part = -ssum;
  if (c == 0 && cl_ == 0) {  // lanes q=0..3 of the c==0 wave of each jt
#pragma unroll
    for (int reg = 0; reg < 4; ++reg) {
      const int Rl = jt * 16 + q * 4 + reg;
      const float mx = fmaxf(lmx[0][Rl], lmx[1][Rl]);
      part += mx + __logf(lsm[0][Rl] + lsm[1][Rl]);
    }
  }
#pragma unroll
  for (int mk = 1; mk < 64; mk <<= 1) part += __shfl_xor(part, mk, 64);
  if (lane == 0) bred[wid] = part;
  __syncthreads();
  if (tid == 0) atomicAdd(out, bred[0] + bred[1] + bred[2] + bred[3]);
}

extern "C" void kernel_launch(void* const* d_in, const int* in_sizes, int n_in,
                              void* d_out, int out_size, void* d_ws, size_t ws_size,
                              hipStream_t stream) {
  const float* e = (const float*)d_in[0];
  const float* wp = (const float*)d_in[1];
  const float* bp = (const float*)d_in[2];
  float* out = (float*)d_out;
  uint4* Cbf = (uint4*)d_ws;  // 1 MB

  k_cent<<<B * N, 256, 0, stream>>>(e, Cbf, out);
  k_gemm3<<<B * 128, 256, 0, stream>>>(e, Cbf, wp, bp, out);
}

// Round 6
// 98.374 us; speedup vs baseline: 1.7576x; 1.0435x over previous
//
#include <hip/hip_runtime.h>

// B=8, N=256, M=16, D=256
// loss = sum_rows logsumexp_k(S) - sum S_self, S = w*<e,c_k>+b, LOO diagonal
constexpr int B = 8, N = 256, M = 16, D = 256;

typedef short bf16x8 __attribute__((ext_vector_type(8)));
typedef float f32x4 __attribute__((ext_vector_type(4)));

__device__ __forceinline__ unsigned short f2bf(float x) {
  unsigned u = __float_as_uint(x);
  u = (u + 0x7FFFu + ((u >> 16) & 1u)) >> 16;  // RNE
  return (unsigned short)u;
}
__device__ __forceinline__ uint4 packbf8(const float* f) {
  uint4 u;
  u.x = (unsigned)f2bf(f[0]) | ((unsigned)f2bf(f[1]) << 16);
  u.y = (unsigned)f2bf(f[2]) | ((unsigned)f2bf(f[3]) << 16);
  u.z = (unsigned)f2bf(f[4]) | ((unsigned)f2bf(f[5]) << 16);
  u.w = (unsigned)f2bf(f[6]) | ((unsigned)f2bf(f[7]) << 16);
  return u;
}

// ws: EbfA [0,16MB) A-frags: uint4[(b*256+j)*8+kc][lane], lane l = row m=l&15,
//       dims kc*32+(l>>4)*8..+7.  Cbf [16,17MB) B-frags: uint4[(b*8+kc)*16+nt][lane],
//       lane l = col n=nt*16+(l&15), dims kc*32+(l>>4)*8..+7.  SQ [17MB,+128KB) fp32 row sqnorms.

// k_prep (round-1 verified, 96.3 us total): one block per (b,j).
// Shuffle-free centroid (thread=dim, serial over M), A-frag pack + sqnorm from
// an L1-hot re-read in (row, octet-pair) ownership. 2 cross-lane ops/thread.
__global__ __launch_bounds__(256) void k_prep(const float* __restrict__ e,
                                              uint4* __restrict__ EbfA,
                                              uint4* __restrict__ Cbf,
                                              float* __restrict__ SQ,
                                              float* __restrict__ out) {
  const int blk = blockIdx.x;  // b*256 + j
  const int b = blk >> 8, j = blk & 255;
  const int t = threadIdx.x;
  const float* base = e + (size_t)blk * (M * D);

  __shared__ float cbuf[D];
  __shared__ float sqred[4][16];

  // Pass 1: centroid. Thread t owns dim d=t; 16 fully-coalesced 1KB loads.
  float cs = 0.f;
#pragma unroll
  for (int i = 0; i < M; ++i) cs += base[i * D + t];
  cbuf[t] = cs * (1.f / 16.f);

  // Pass 2: A-frag pack + sqnorm. Thread t -> row m=t&15, octet pair {o2, o2+16}.
  const int m = t & 15, o2 = t >> 4;
  const float* p0 = base + m * D + o2 * 8;  // 32B-aligned
  float f0[8], f1[8];
  *(float4*)(f0) = *(const float4*)(p0);
  *(float4*)(f0 + 4) = *(const float4*)(p0 + 4);
  *(float4*)(f1) = *(const float4*)(p0 + 128);
  *(float4*)(f1 + 4) = *(const float4*)(p0 + 132);

  // A-fragment stores: octet o -> slot kc=o>>2, lane (o&3)*16+m.
  // t-ascending => uint4 addresses perfectly sequential (1KB contiguous per wave).
  EbfA[(size_t)(blk * 8 + (o2 >> 2)) * 64 + (o2 & 3) * 16 + m] = packbf8(f0);
  EbfA[(size_t)(blk * 8 + 4 + (o2 >> 2)) * 64 + (o2 & 3) * 16 + m] = packbf8(f1);

  // sqnorm partial: dims [o2*8,+8) u [128+o2*8,+8) of row m.
  float sqp = 0.f;
#pragma unroll
  for (int x = 0; x < 8; ++x) sqp = fmaf(f0[x], f0[x], fmaf(f1[x], f1[x], sqp));
  sqp += __shfl_xor(sqp, 16, 64);
  sqp += __shfl_xor(sqp, 32, 64);
  const int w = t >> 6;
  if ((t & 63) < 16) sqred[w][m] = sqp;
  __syncthreads();

  // Epilogue: centroid B-frag pack (threads 0..31: kc=t>>2, q=t&3, dims t*8..+7)
  if (t < 32) {
    float cf[8];
#pragma unroll
    for (int x = 0; x < 8; ++x) cf[x] = cbuf[t * 8 + x];
    Cbf[((size_t)(b * 8 + (t >> 2)) * 16 + (j >> 4)) * 64 + (t & 3) * 16 + (j & 15)] =
        packbf8(cf);
  }
  if (t < 16) SQ[blk * 16 + t] = sqred[0][t] + sqred[1][t] + sqred[2][t] + sqred[3][t];
  if (blk == 0 && t == 0) out[0] = 0.f;  // d_out re-poisoned each launch
}

// One block per (b, 64-row strip). 4 waves 2x2: h=row-half(2 tiles), c=col-half(8 tiles).
// acc 64 VGPRs/wave; NO dynamic register indexing anywhere.
__global__ __launch_bounds__(256) void k_gemm(const uint4* __restrict__ EbfA,
                                              const uint4* __restrict__ Cbf,
                                              const float* __restrict__ SQ,
                                              const float* __restrict__ wp,
                                              const float* __restrict__ bp,
                                              float* __restrict__ out) {
  const int blk = blockIdx.x;  // b*64 + strip
  const int b = blk >> 6, strip = blk & 63;
  const int tid = threadIdx.x;
  const int wid = tid >> 6, lane = tid & 63;
  const int h = wid >> 1, c = wid & 1;
  const int q = lane >> 4, cl_ = lane & 15;

  const uint4* Ab = EbfA + (size_t)((b * 256 + strip * 4 + h * 2) * 8) * 64 + lane;
  const uint4* Bb = Cbf + (size_t)(b * 128 + c * 8) * 64 + lane;

  f32x4 acc[2][8];
#pragma unroll
  for (int rt = 0; rt < 2; ++rt)
#pragma unroll
    for (int nt = 0; nt < 8; ++nt) acc[rt][nt] = (f32x4)0.f;

#pragma unroll 1
  for (int kc = 0; kc < 8; ++kc) {
    uint4 af0 = Ab[kc * 64];
    uint4 af1 = Ab[(8 + kc) * 64];
    uint4 bfr[8];
#pragma unroll
    for (int nt = 0; nt < 8; ++nt) bfr[nt] = Bb[(kc * 16 + nt) * 64];
    bf16x8 a0 = __builtin_bit_cast(bf16x8, af0);
    bf16x8 a1 = __builtin_bit_cast(bf16x8, af1);
#pragma unroll
    for (int nt = 0; nt < 8; ++nt) {
      bf16x8 bv = __builtin_bit_cast(bf16x8, bfr[nt]);
      acc[0][nt] = __builtin_amdgcn_mfma_f32_16x16x32_bf16(a0, bv, acc[0][nt], 0, 0, 0);
      acc[1][nt] = __builtin_amdgcn_mfma_f32_16x16x32_bf16(a1, bv, acc[1][nt], 0, 0, 0);
    }
  }

  // ---- epilogue: scale, LOO diagonal, logsumexp ----
  const float w = *wp, bias = *bp;
  __shared__ float lmx[2][64];
  __shared__ float lsm[2][64];
  __shared__ float bred[4];
  float ssum = 0.f;

#pragma unroll
  for (int rt = 0; rt < 2; ++rt) {
    const int jr = strip * 4 + h * 2 + rt;          // global row-tile == diag col
    const bool own = (c == (jr >> 7)) && (cl_ == (jr & 15));
    const int ntd = (jr >> 4) & 7;
    float sq[4];
    if (own) {
#pragma unroll
      for (int reg = 0; reg < 4; ++reg)
        sq[reg] = SQ[b * 4096 + strip * 64 + (h * 2 + rt) * 16 + q * 4 + reg];
    }
#pragma unroll
    for (int nt = 0; nt < 8; ++nt)
#pragma unroll
      for (int reg = 0; reg < 4; ++reg) {
        const float raw = acc[rt][nt][reg];
        float sv = fmaf(w, raw, bias);
        if (own && nt == ntd) {                      // predicated select, no indexing
          sv = fmaf(w * (1.f / 15.f), 16.f * raw - sq[reg], bias);
          ssum += sv;
        }
        acc[rt][nt][reg] = sv;
      }
#pragma unroll
    for (int reg = 0; reg < 4; ++reg) {
      float mx = acc[rt][0][reg];
#pragma unroll
      for (int nt = 1; nt < 8; ++nt) mx = fmaxf(mx, acc[rt][nt][reg]);
#pragma unroll
      for (int mk = 1; mk < 16; mk <<= 1) mx = fmaxf(mx, __shfl_xor(mx, mk, 64));
      if (cl_ == 0) lmx[c][(h * 2 + rt) * 16 + q * 4 + reg] = mx;
    }
  }
  __syncthreads();

#pragma unroll
  for (int rt = 0; rt < 2; ++rt)
#pragma unroll
    for (int reg = 0; reg < 4; ++reg) {
      const int Rl = (h * 2 + rt) * 16 + q * 4 + reg;
      const float mx = fmaxf(lmx[0][Rl], lmx[1][Rl]);
      float se = 0.f;
#pragma unroll
      for (int nt = 0; nt < 8; ++nt) se += __expf(acc[rt][nt][reg] - mx);
#pragma unroll
      for (int mk = 1; mk < 16; mk <<= 1) se += __shfl_xor(se, mk, 64);
      if (cl_ == 0) lsm[c][Rl] = se;
    }
  __syncthreads();

  float part = -ssum;
  if (c == 0 && cl_ == 0) {
#pragma unroll
    for (int rt = 0; rt < 2; ++rt)
#pragma unroll
      for (int reg = 0; reg < 4; ++reg) {
        const int Rl = (h * 2 + rt) * 16 + q * 4 + reg;
        const float mx = fmaxf(lmx[0][Rl], lmx[1][Rl]);
        part += mx + __logf(lsm[0][Rl] + lsm[1][Rl]);
      }
  }
#pragma unroll
  for (int mk = 1; mk < 64; mk <<= 1) part += __shfl_xor(part, mk, 64);
  if (lane == 0) bred[wid] = part;
  __syncthreads();
  if (tid == 0) atomicAdd(out, bred[0] + bred[1] + bred[2] + bred[3]);
}

extern "C" void kernel_launch(void* const* d_in, const int* in_sizes, int n_in,
                              void* d_out, int out_size, void* d_ws, size_t ws_size,
                              hipStream_t stream) {
  const float* e = (const float*)d_in[0];
  const float* wp = (const float*)d_in[1];
  const float* bp = (const float*)d_in[2];
  float* out = (float*)d_out;
  char* ws = (char*)d_ws;
  uint4* EbfA = (uint4*)ws;                              // 16 MB
  uint4* Cbf = (uint4*)(ws + (size_t)16 * 1024 * 1024);  // 1 MB
  float* SQ = (float*)(ws + (size_t)17 * 1024 * 1024);   // 128 KB

  k_prep<<<B * N, 256, 0, stream>>>(e, EbfA, Cbf, SQ, out);
  k_gemm<<<B * 64, 256, 0, stream>>>(EbfA, Cbf, SQ, wp, bp, out);
}